// Round 6
// baseline (92.484 us; speedup 1.0000x reference)
//
#include <hip/hip_runtime.h>

namespace {
constexpr int Bn = 8, LQ = 512, LK = 512, Dn = 64;
constexpr int T = 512, QT = 16, KT = 128, NT = LK / KT;   // 4 k-tiles
constexpr float C2 = 2.8853900817779268f;                 // 2*log2(e)

// score(b,q,k) = sum_d tanh(q_d+k_d) = 64 - 2a, a = sum_d rcp(1 + e^{2q_d}e^{2k_d})
// p = e^{score-64} = exp2(-C2*a); a in (0,64) -> no overflow; softmax exact.

__device__ __forceinline__ void gl_lds16(const float* g, float* l) {
  __builtin_amdgcn_global_load_lds(
      (const __attribute__((address_space(1))) void*)g,
      (__attribute__((address_space(3))) void*)l, 16, 0, 0);
}

// prep: eqG = exp2(C2*Q) linear; ekG = exp2(C2*K) with column XOR-swizzle
// (c ^= (row&7)*4) so the main kernel's lane=k column reads are conflict-free.
__global__ __launch_bounds__(256)
void prep(const float* __restrict__ Q, const float* __restrict__ K,
          float* __restrict__ eqG, float* __restrict__ ekG) {
  const int g = blockIdx.x * 256 + threadIdx.x;   // 0..262143
  const int row = g >> 6, c = g & 63;
  eqG[g] = __builtin_amdgcn_exp2f(Q[g] * C2);
  ekG[row * 64 + (c ^ ((row & 7) * 4))] = __builtin_amdgcn_exp2f(K[g] * C2);
}

__global__ __launch_bounds__(T, 2)
void addattn(const float* __restrict__ eqG, const float* __restrict__ ekG,
             const float* __restrict__ V, float* __restrict__ O)
{
  __shared__ __align__(16) float ekL[2][KT][Dn];  // 64KB, swizzled cols
  __shared__ __align__(16) float vL [2][KT][Dn];  // 64KB, linear
  __shared__ __align__(16) float pL [QT][132];    // 8.25KB
  __shared__ float scrD[8][4];                    // per-wave denom partials

  const int t    = threadIdx.x;
  const int bb   = blockIdx.x >> 5;          // batch
  const int q0   = (blockIdx.x & 31) * QT;   // q-block base
  const int w    = t >> 6;
  const int lane = t & 63;
  const int qhu  = __builtin_amdgcn_readfirstlane(w >> 1);  // q-quad (0..3)
  const int khu  = __builtin_amdgcn_readfirstlane(w & 1);   // k-half (0..1)
  const int dq   = lane & 15;                // PV: d-quad
  const int kg   = lane >> 4;                // PV: k-group of 16
  const int sw   = (lane & 7) * 4;           // score read swizzle (myk&7 == lane&7)

  const float* eqw = eqG + (size_t)(bb * LQ + q0 + qhu * 4) * Dn;  // 4 q-rows (uniform)
  const float* ekB = ekG + (size_t)(bb * LK) * Dn;
  const float* vB  = V   + (size_t)(bb * LK) * Dn;

  auto stage = [&](int buf, int k0) {
    const float* gs = ekB + (size_t)k0 * Dn;
    const float* vs = vB  + (size_t)k0 * Dn;
    float* le = &ekL[buf][0][0];
    float* lv = &vL [buf][0][0];
    #pragma unroll
    for (int r = 0; r < 4; ++r) {           // 4 rounds x 512 thr x 16B = 32KB each
      gl_lds16(gs + r * 2048 + t * 4, le + r * 2048 + t * 4);
      gl_lds16(vs + r * 2048 + t * 4, lv + r * 2048 + t * 4);
    }
  };

  stage(0, 0);
  __syncthreads();                           // tile 0 staged (vmcnt drained)

  float acc[4][4];                           // [qi][dc] PV partials
  #pragma unroll
  for (int qi = 0; qi < 4; ++qi) {
    acc[qi][0] = 0.f; acc[qi][1] = 0.f; acc[qi][2] = 0.f; acc[qi][3] = 0.f;
  }
  float ds4[4] = {0.f, 0.f, 0.f, 0.f};       // denom partials (lane's k)

  for (int tile = 0; tile < NT; ++tile) {
    const int buf = tile & 1;
    if (tile + 1 < NT) stage(buf ^ 1, (tile + 1) * KT);

    // ---- score: lane = k (khu half), 4 q-rows; ek swizzled-full-rate, eq off-LDS
    {
      const float* ekrow = &ekL[buf][khu * 64 + lane][0];
      float a0[4] = {0.f, 0.f, 0.f, 0.f};
      float a1[4] = {0.f, 0.f, 0.f, 0.f};
      #pragma unroll
      for (int d4 = 0; d4 < 16; ++d4) {
        const float4 x  = *(const float4*)(ekrow + ((d4 * 4) ^ sw));
        const float4 e0 = *(const float4*)(eqw + 0 * Dn + d4 * 4);
        const float4 e1 = *(const float4*)(eqw + 1 * Dn + d4 * 4);
        const float4 e2 = *(const float4*)(eqw + 2 * Dn + d4 * 4);
        const float4 e3 = *(const float4*)(eqw + 3 * Dn + d4 * 4);
        a0[0] += __builtin_amdgcn_rcpf(fmaf(e0.x, x.x, 1.f));
        a1[0] += __builtin_amdgcn_rcpf(fmaf(e0.y, x.y, 1.f));
        a0[0] += __builtin_amdgcn_rcpf(fmaf(e0.z, x.z, 1.f));
        a1[0] += __builtin_amdgcn_rcpf(fmaf(e0.w, x.w, 1.f));
        a0[1] += __builtin_amdgcn_rcpf(fmaf(e1.x, x.x, 1.f));
        a1[1] += __builtin_amdgcn_rcpf(fmaf(e1.y, x.y, 1.f));
        a0[1] += __builtin_amdgcn_rcpf(fmaf(e1.z, x.z, 1.f));
        a1[1] += __builtin_amdgcn_rcpf(fmaf(e1.w, x.w, 1.f));
        a0[2] += __builtin_amdgcn_rcpf(fmaf(e2.x, x.x, 1.f));
        a1[2] += __builtin_amdgcn_rcpf(fmaf(e2.y, x.y, 1.f));
        a0[2] += __builtin_amdgcn_rcpf(fmaf(e2.z, x.z, 1.f));
        a1[2] += __builtin_amdgcn_rcpf(fmaf(e2.w, x.w, 1.f));
        a0[3] += __builtin_amdgcn_rcpf(fmaf(e3.x, x.x, 1.f));
        a1[3] += __builtin_amdgcn_rcpf(fmaf(e3.y, x.y, 1.f));
        a0[3] += __builtin_amdgcn_rcpf(fmaf(e3.z, x.z, 1.f));
        a1[3] += __builtin_amdgcn_rcpf(fmaf(e3.w, x.w, 1.f));
      }
      #pragma unroll
      for (int qi = 0; qi < 4; ++qi) {
        const float p = __builtin_amdgcn_exp2f(-C2 * (a0[qi] + a1[qi]));
        ds4[qi] += p;
        pL[qhu * 4 + qi][khu * 64 + lane] = p;   // wave-private row+col range
      }
    }

    // ---- p chunk -> regs (own wave's writes; lgkmcnt-ordered, no barrier)
    float pcf[4][16];
    #pragma unroll
    for (int qi = 0; qi < 4; ++qi)
      #pragma unroll
      for (int jq = 0; jq < 4; ++jq)
        *(float4*)&pcf[qi][jq * 4] =
            *(const float4*)&pL[qhu * 4 + qi][khu * 64 + kg * 16 + jq * 4];

    // ---- PV: lane=(dq,kg); 1 full-rate V b128 feeds 16 fma
    {
      const float* vbase = &vL[buf][khu * 64 + kg * 16][0] + dq * 4;
      #pragma unroll
      for (int j = 0; j < 16; ++j) {
        const float4 v4 = *(const float4*)(vbase + j * Dn);
        #pragma unroll
        for (int qi = 0; qi < 4; ++qi) {
          const float pj = pcf[qi][j];
          acc[qi][0] = fmaf(pj, v4.x, acc[qi][0]);
          acc[qi][1] = fmaf(pj, v4.y, acc[qi][1]);
          acc[qi][2] = fmaf(pj, v4.z, acc[qi][2]);
          acc[qi][3] = fmaf(pj, v4.w, acc[qi][3]);
        }
      }
    }

    __syncthreads();   // one barrier/tile: next tile staged, pL/ekL/vL safe
  }

  // ---- epilogue: denom reduce (per wave) + O partial reduce over 8 slices
  #pragma unroll
  for (int qi = 0; qi < 4; ++qi) {
    float s = ds4[qi];
    #pragma unroll
    for (int m = 1; m < 64; m <<= 1) s += __shfl_xor(s, m);
    if (lane == 0) scrD[w][qi] = s;
  }

  float* scr = &ekL[0][0][0];               // reuse: [8 slices][16 q][64 d] = 32KB
  const int slice = khu * 4 + kg;
  #pragma unroll
  for (int qi = 0; qi < 4; ++qi)
    *(float4*)(scr + (size_t)(slice * QT + qhu * 4 + qi) * Dn + dq * 4) =
        make_float4(acc[qi][0], acc[qi][1], acc[qi][2], acc[qi][3]);
  __syncthreads();

  if (t < 256) {
    const int r = t >> 4, d4c = t & 15;
    float4 o = make_float4(0.f, 0.f, 0.f, 0.f);
    #pragma unroll
    for (int s8 = 0; s8 < 8; ++s8) {
      const float4 c = *(const float4*)(scr + (size_t)(s8 * QT + r) * Dn + d4c * 4);
      o.x += c.x; o.y += c.y; o.z += c.z; o.w += c.w;
    }
    const int rqh = r >> 2, rqi = r & 3;
    const float inv = 1.0f / (scrD[rqh * 2 + 0][rqi] + scrD[rqh * 2 + 1][rqi]);
    o.x *= inv; o.y *= inv; o.z *= inv; o.w *= inv;
    *(float4*)(O + (size_t)(bb * LQ + q0 + r) * Dn + d4c * 4) = o;
  }
}
} // namespace

extern "C" void kernel_launch(void* const* d_in, const int* in_sizes, int n_in,
                              void* d_out, int out_size, void* d_ws, size_t ws_size,
                              hipStream_t stream) {
  (void)in_sizes; (void)n_in; (void)out_size; (void)ws_size;
  const float* Q = (const float*)d_in[0];
  const float* K = (const float*)d_in[1];
  const float* V = (const float*)d_in[2];
  float* O   = (float*)d_out;
  float* eqG = (float*)d_ws;                       // 4096x64 f32 = 1MB
  float* ekG = eqG + (size_t)Bn * LQ * Dn;         // 4096x64 f32 = 1MB (swizzled)
  prep<<<dim3(Bn * LK * Dn / 256), dim3(256), 0, stream>>>(Q, K, eqG, ekG);
  addattn<<<dim3(Bn * (LQ / QT)), dim3(T), 0, stream>>>(eqG, ekG, V, O);
}

// Round 8
// 83.395 us; speedup vs baseline: 1.1090x; 1.1090x over previous
//
#include <hip/hip_runtime.h>

namespace {
constexpr int Bn = 8, LQ = 512, LK = 512, Dn = 64;
constexpr int T = 512, QT = 8, KT = 64, NT = LK / KT;
constexpr float C2 = 2.8853900817779268f;   // 2*log2(e)

// score(b,q,k) = sum_d tanh(q_d+k_d) = 64 - 2a, a = sum_d rcp(1 + e^{2q_d}e^{2k_d})
// p = e^{score-64} = exp2(-C2*a); a in (0,64) -> no overflow; softmax exact.

__device__ __forceinline__ void gl_lds16(const float* g, float* l) {
  __builtin_amdgcn_global_load_lds(
      (const __attribute__((address_space(1))) void*)g,
      (__attribute__((address_space(3))) void*)l, 16, 0, 0);
}

__global__ __launch_bounds__(T, 4)
void addattn(const float* __restrict__ Q, const float* __restrict__ K,
             const float* __restrict__ V, float* __restrict__ O)
{
  __shared__ __align__(16) float ekL[2][KT][68];  // 34.8KB; pad 68
  __shared__ __align__(16) float vL [2][KT][Dn];  // 32.8KB; LINEAR (global_load_lds)
  __shared__ __align__(16) float pL [QT][68];     // 2.2KB
  __shared__ float scrD[2][QT];

  const int t    = threadIdx.x;
  const int w    = t >> 6;
  const int lane = t & 63;
  const int qq   = w >> 1;            // 0..3 -> q rows qq*2, qq*2+1
  const int kq   = w & 1;             // 0..1 -> 32-k strip of tile
  const int dsub = lane & 3;          // score: d-slice of 16 floats
  const int k16  = lane >> 2;         // score: k-slot (0..15)
  const int pq   = lane >> 5;         // PV: q (0..1)
  const int kh   = (lane >> 4) & 1;   // PV: k-half of strip
  const int dq   = lane & 15;         // PV: d-quad
  const int srow = t >> 3;            // K staging: tile row (ds_write, any map ok)
  const int scol = (t & 7) * 8;       // K staging: col base
  const int bb   = blockIdx.x >> 6;
  const int q0   = (blockIdx.x & 63) * QT;

  const float* Kt = K + (size_t)bb * LK * Dn;
  const float* Vt = V + (size_t)bb * LK * Dn;

  // V staging: MUST be linear-in-thread (global_load_lds = wave base + lane*16B)
  auto stageV = [&](int buf, int k0) {
    const float* vs = Vt + (size_t)k0 * Dn;
    float* lv = &vL[buf][0][0];
    gl_lds16(vs + t * 4,        lv + t * 4);
    gl_lds16(vs + 2048 + t * 4, lv + 2048 + t * 4);
  };

  // ---- eq = exp(2q) in registers: lane holds d-slice [dsub*16, +16) of 2 q-rows
  float4 eqr[8];
  #pragma unroll
  for (int q = 0; q < 2; ++q) {
    #pragma unroll
    for (int j = 0; j < 4; ++j) {
      float4 v = *(const float4*)(Q + (size_t)(bb * LQ + q0 + qq * 2 + q) * Dn
                                  + dsub * 16 + j * 4);
      v.x = __builtin_amdgcn_exp2f(v.x * C2);
      v.y = __builtin_amdgcn_exp2f(v.y * C2);
      v.z = __builtin_amdgcn_exp2f(v.z * C2);
      v.w = __builtin_amdgcn_exp2f(v.w * C2);
      eqr[q * 4 + j] = v;
    }
  }

  // ---- stage tile 0
  stageV(0, 0);
  {
    const float* kx = Kt + (size_t)srow * Dn + scol;
    float4 ka = *(const float4*)kx;
    float4 kb = *(const float4*)(kx + 4);
    float4 ea, eb;
    ea.x = __builtin_amdgcn_exp2f(ka.x * C2);
    ea.y = __builtin_amdgcn_exp2f(ka.y * C2);
    ea.z = __builtin_amdgcn_exp2f(ka.z * C2);
    ea.w = __builtin_amdgcn_exp2f(ka.w * C2);
    eb.x = __builtin_amdgcn_exp2f(kb.x * C2);
    eb.y = __builtin_amdgcn_exp2f(kb.y * C2);
    eb.z = __builtin_amdgcn_exp2f(kb.z * C2);
    eb.w = __builtin_amdgcn_exp2f(kb.w * C2);
    *(float4*)&ekL[0][srow][scol]     = ea;
    *(float4*)&ekL[0][srow][scol + 4] = eb;
  }
  __syncthreads();

  float dsum0 = 0.f, dsum1 = 0.f;
  float4 acc = make_float4(0.f, 0.f, 0.f, 0.f);

  for (int tile = 0; tile < NT; ++tile) {
    const int buf = tile & 1;
    const bool more = (tile + 1 < NT);
    float4 nk0, nk1;
    if (more) {
      const int kb = (tile + 1) * KT;
      stageV(buf ^ 1, kb);
      const float* kx = Kt + (size_t)(kb + srow) * Dn + scol;
      nk0 = *(const float4*)kx;
      nk1 = *(const float4*)(kx + 4);
    }

    // ---- score: per ki, 4 ek b128 feed 32 rcp (2 q-rows); DPP quad reduce
    #pragma unroll
    for (int ki = 0; ki < 2; ++ki) {
      const int kcol = kq * 32 + ki * 16 + k16;
      const float* ekr = &ekL[buf][kcol][dsub * 16];
      const float4 x0 = *(const float4*)(ekr);
      const float4 x1 = *(const float4*)(ekr + 4);
      const float4 x2 = *(const float4*)(ekr + 8);
      const float4 x3 = *(const float4*)(ekr + 12);
      float a0 = 0.f, b0 = 0.f, a1 = 0.f, b1 = 0.f;
      {
        const float4 e0 = eqr[0], e1 = eqr[1], e2 = eqr[2], e3 = eqr[3];
        a0 += __builtin_amdgcn_rcpf(fmaf(e0.x, x0.x, 1.f));
        a0 += __builtin_amdgcn_rcpf(fmaf(e0.y, x0.y, 1.f));
        a0 += __builtin_amdgcn_rcpf(fmaf(e0.z, x0.z, 1.f));
        a0 += __builtin_amdgcn_rcpf(fmaf(e0.w, x0.w, 1.f));
        a0 += __builtin_amdgcn_rcpf(fmaf(e1.x, x1.x, 1.f));
        a0 += __builtin_amdgcn_rcpf(fmaf(e1.y, x1.y, 1.f));
        a0 += __builtin_amdgcn_rcpf(fmaf(e1.z, x1.z, 1.f));
        a0 += __builtin_amdgcn_rcpf(fmaf(e1.w, x1.w, 1.f));
        b0 += __builtin_amdgcn_rcpf(fmaf(e2.x, x2.x, 1.f));
        b0 += __builtin_amdgcn_rcpf(fmaf(e2.y, x2.y, 1.f));
        b0 += __builtin_amdgcn_rcpf(fmaf(e2.z, x2.z, 1.f));
        b0 += __builtin_amdgcn_rcpf(fmaf(e2.w, x2.w, 1.f));
        b0 += __builtin_amdgcn_rcpf(fmaf(e3.x, x3.x, 1.f));
        b0 += __builtin_amdgcn_rcpf(fmaf(e3.y, x3.y, 1.f));
        b0 += __builtin_amdgcn_rcpf(fmaf(e3.z, x3.z, 1.f));
        b0 += __builtin_amdgcn_rcpf(fmaf(e3.w, x3.w, 1.f));
      }
      {
        const float4 e0 = eqr[4], e1 = eqr[5], e2 = eqr[6], e3 = eqr[7];
        a1 += __builtin_amdgcn_rcpf(fmaf(e0.x, x0.x, 1.f));
        a1 += __builtin_amdgcn_rcpf(fmaf(e0.y, x0.y, 1.f));
        a1 += __builtin_amdgcn_rcpf(fmaf(e0.z, x0.z, 1.f));
        a1 += __builtin_amdgcn_rcpf(fmaf(e0.w, x0.w, 1.f));
        a1 += __builtin_amdgcn_rcpf(fmaf(e1.x, x1.x, 1.f));
        a1 += __builtin_amdgcn_rcpf(fmaf(e1.y, x1.y, 1.f));
        a1 += __builtin_amdgcn_rcpf(fmaf(e1.z, x1.z, 1.f));
        a1 += __builtin_amdgcn_rcpf(fmaf(e1.w, x1.w, 1.f));
        b1 += __builtin_amdgcn_rcpf(fmaf(e2.x, x2.x, 1.f));
        b1 += __builtin_amdgcn_rcpf(fmaf(e2.y, x2.y, 1.f));
        b1 += __builtin_amdgcn_rcpf(fmaf(e2.z, x2.z, 1.f));
        b1 += __builtin_amdgcn_rcpf(fmaf(e2.w, x2.w, 1.f));
        b1 += __builtin_amdgcn_rcpf(fmaf(e3.x, x3.x, 1.f));
        b1 += __builtin_amdgcn_rcpf(fmaf(e3.y, x3.y, 1.f));
        b1 += __builtin_amdgcn_rcpf(fmaf(e3.z, x3.z, 1.f));
        b1 += __builtin_amdgcn_rcpf(fmaf(e3.w, x3.w, 1.f));
      }
      float s0 = a0 + b0, s1 = a1 + b1;
      s0 += __shfl_xor(s0, 1);  s0 += __shfl_xor(s0, 2);   // quad-perm (VALU pipe)
      s1 += __shfl_xor(s1, 1);  s1 += __shfl_xor(s1, 2);
      const float p0 = __builtin_amdgcn_exp2f(-C2 * s0);
      const float p1 = __builtin_amdgcn_exp2f(-C2 * s1);
      dsum0 += p0;
      dsum1 += p1;
      if (dsub < 2) pL[qq * 2 + dsub][kcol] = dsub ? p1 : p0;
    }

    // ---- PV: lane=(pq,kh,dq); p -> regs via b128, V from front buffer
    {
      const float* pr = &pL[qq * 2 + pq][kq * 32 + kh * 16];
      float pcf[16];
      #pragma unroll
      for (int j4 = 0; j4 < 4; ++j4)
        *(float4*)&pcf[j4 * 4] = *(const float4*)(pr + j4 * 4);
      const float* vb = &vL[buf][kq * 32 + kh * 16][dq * 4];
      #pragma unroll
      for (int j = 0; j < 16; ++j) {
        const float4 v4 = *(const float4*)(vb + j * Dn);
        const float  pw = pcf[j];
        acc.x = fmaf(pw, v4.x, acc.x);
        acc.y = fmaf(pw, v4.y, acc.y);
        acc.z = fmaf(pw, v4.z, acc.z);
        acc.w = fmaf(pw, v4.w, acc.w);
      }
    }

    // ---- write next K tile into back buffer
    if (more) {
      float4 ea, eb;
      ea.x = __builtin_amdgcn_exp2f(nk0.x * C2);
      ea.y = __builtin_amdgcn_exp2f(nk0.y * C2);
      ea.z = __builtin_amdgcn_exp2f(nk0.z * C2);
      ea.w = __builtin_amdgcn_exp2f(nk0.w * C2);
      eb.x = __builtin_amdgcn_exp2f(nk1.x * C2);
      eb.y = __builtin_amdgcn_exp2f(nk1.y * C2);
      eb.z = __builtin_amdgcn_exp2f(nk1.z * C2);
      eb.w = __builtin_amdgcn_exp2f(nk1.w * C2);
      *(float4*)&ekL[buf ^ 1][srow][scol]     = ea;
      *(float4*)&ekL[buf ^ 1][srow][scol + 4] = eb;
    }

    __syncthreads();   // one barrier/tile (drains gl_lds + ds_writes)
  }

  // ---- epilogue: denom reduce over k16 lanes (bits 2..5), then cross-wave
  float s0 = dsum0, s1 = dsum1;
  #pragma unroll
  for (int m = 4; m < 64; m <<= 1) {
    s0 += __shfl_xor(s0, m);
    s1 += __shfl_xor(s1, m);
  }
  if (lane == 0) {
    scrD[kq][qq * 2 + 0] = s0;
    scrD[kq][qq * 2 + 1] = s1;
  }

  float* scrO = &ekL[0][0][0];   // reuse: [4 slices][8 q][64 d] = 8KB
  *(float4*)(scrO + (size_t)(((kq * 2 + kh) * 8) + qq * 2 + pq) * 64 + dq * 4) = acc;
  __syncthreads();

  if (t < 128) {
    const int r = t >> 4, d4 = t & 15;
    float4 o = make_float4(0.f, 0.f, 0.f, 0.f);
    #pragma unroll
    for (int s = 0; s < 4; ++s) {
      const float4 c = *(const float4*)(scrO + (size_t)(s * 8 + r) * 64 + d4 * 4);
      o.x += c.x; o.y += c.y; o.z += c.z; o.w += c.w;
    }
    const float inv = 1.0f / (scrD[0][r] + scrD[1][r]);
    o.x *= inv; o.y *= inv; o.z *= inv; o.w *= inv;
    *(float4*)(O + (size_t)(bb * LQ + q0 + r) * Dn + d4 * 4) = o;
  }
}
} // namespace

extern "C" void kernel_launch(void* const* d_in, const int* in_sizes, int n_in,
                              void* d_out, int out_size, void* d_ws, size_t ws_size,
                              hipStream_t stream) {
  (void)in_sizes; (void)n_in; (void)d_ws; (void)ws_size; (void)out_size;
  const float* Q = (const float*)d_in[0];
  const float* K = (const float*)d_in[1];
  const float* V = (const float*)d_in[2];
  float* O = (float*)d_out;
  addattn<<<dim3(Bn * (LQ / QT)), dim3(T), 0, stream>>>(Q, K, V, O);
}